// Round 1
// baseline (1996.984 us; speedup 1.0000x reference)
//
#include <hip/hip_runtime.h>
#include <math.h>

#define KCOMP 128
#define DF    1024
#define LF    16
#define NPTS  16384

#define BN 128
#define BK 8
#define DT 32

// ws layout (floats)
#define WS_IL   0                  // K*256  inverse of Lm, row-major 16x16 per k
#define WS_B    (KCOMP*256)        // K*16   b[k][l] = sum_d MU*iD*A[:,l]
#define WS_C3   (WS_B + KCOMP*16)  // K      c3[k]  = sum_d iD*MU^2
#define WS_CST  (WS_C3 + KCOMP)    // K      PI[k] - 0.5*(DF*log2pi + logdetSigma)

// ---------------------------------------------------------------------------
// Precompute: one block (256 thr) per component k.
// Accumulate Lm = I + A^T iD A (16x16), b, c3, sum(log iD); then Gauss-Jordan
// invert Lm in LDS (SPD, diagonally dominant -> no pivoting), accumulating
// log-det from the pivots.
// ---------------------------------------------------------------------------
__global__ __launch_bounds__(256) void mfa_pre(
    const float* __restrict__ PI, const float* __restrict__ MU,
    const float* __restrict__ A, const float* __restrict__ Dm,
    float* __restrict__ ws)
{
  const int k = blockIdx.x;
  const int t = threadIdx.x;
  const int tl = t >> 4, tm = t & 15;

  __shared__ float As[16][16];          // [dd][l]
  __shared__ float iDsh[16], MUsh[16];
  __shared__ float M[16][17], Iv[16][17];
  __shared__ float piv_s, ldet_s;

  float accL = 0.f, accb = 0.f, accc3 = 0.f, accsl = 0.f;

  for (int d0 = 0; d0 < DF; d0 += 16) {
    __syncthreads();
    As[tl][tm] = A[(size_t)(k*DF + d0 + tl)*LF + tm];
    if (t < 16) {
      float dv = Dm[k*DF + d0 + t];
      iDsh[t] = 1.f / (dv*dv);
      MUsh[t] = MU[k*DF + d0 + t];
    }
    __syncthreads();
    #pragma unroll
    for (int dd = 0; dd < 16; ++dd) {
      float w = iDsh[dd];
      accL = fmaf(As[dd][tl]*w, As[dd][tm], accL);
      if (tm == 0) accb = fmaf(MUsh[dd]*w, As[dd][tl], accb);
    }
    if (t == 0) {
      for (int dd = 0; dd < 16; ++dd) {
        accc3 = fmaf(iDsh[dd]*MUsh[dd], MUsh[dd], accc3);
        accsl += logf(iDsh[dd]);
      }
    }
  }
  __syncthreads();
  M[tl][tm]  = accL + (tl == tm ? 1.f : 0.f);
  Iv[tl][tm] = (tl == tm) ? 1.f : 0.f;
  if (t == 0) ldet_s = 0.f;
  __syncthreads();

  for (int i = 0; i < 16; ++i) {
    if (t == 0) { float p = M[i][i]; piv_s = 1.f / p; ldet_s += logf(p); }
    __syncthreads();
    float ip = piv_s;
    if (tl == i) { M[i][tm] *= ip; Iv[i][tm] *= ip; }
    __syncthreads();
    float f = M[tl][i];
    __syncthreads();
    if (tl != i) {
      M[tl][tm]  -= f * M[i][tm];
      Iv[tl][tm] -= f * Iv[i][tm];
    }
    __syncthreads();
  }

  ws[WS_IL + k*256 + t] = Iv[tl][tm];
  if (tm == 0) ws[WS_B + k*16 + tl] = accb;
  if (t == 0) {
    ws[WS_C3 + k] = accc3;
    const float LOG2PI = 1.8378770664093453f;
    float logdetSigma = ldet_s - accsl;
    ws[WS_CST + k] = PI[k] - 0.5f * ((float)DF * LOG2PI + logdetSigma);
  }
}

// ---------------------------------------------------------------------------
// Main: block = 128 n-rows x 8 components, 256 threads.
// Thread (kk = t&7, nr = t>>3) owns 4 n-rows (nr, nr+32, nr+64, nr+96) for one
// component; accumulates y[0:16], s1 = sum iD x^2, s2 = sum iD x MU over d.
// Epilogue: quad = (y-b)^T iL (y-b);  out = cst - 0.5*(s1-2*s2+c3) + 0.5*quad.
// ---------------------------------------------------------------------------
__global__ __launch_bounds__(256) void mfa_main(
    const float* __restrict__ x, const float* __restrict__ A,
    const float* __restrict__ MU, const float* __restrict__ Dm,
    const float* __restrict__ ws, float* __restrict__ out)
{
  __shared__ float xs[DT][BN+1];        // [dd][n], pad 129
  __shared__ float As_[BK*516];         // slab 516 floats/k: DT*LF=512 + 4 pad
  __shared__ float iDs[BK][DT+1];
  __shared__ float MUs[BK][DT+1];
  __shared__ float iLs[BK][257];        // 16x16 row-major + pad
  __shared__ float bs[BK][16];
  __shared__ float c3s[BK], csts[BK];

  const int t  = threadIdx.x;
  const int kk = t & 7;
  const int nr = t >> 3;
  const int n0 = blockIdx.x * BN;
  const int k0 = blockIdx.y * BK;

  // one-time epilogue staging (separate LDS arrays; later barriers publish)
  #pragma unroll
  for (int k2 = 0; k2 < BK; ++k2)
    iLs[k2][t] = ws[WS_IL + (k0+k2)*256 + t];
  if (t < 128) bs[t>>4][t&15] = ws[WS_B + (k0 + (t>>4))*16 + (t&15)];
  if (t < BK) { c3s[t] = ws[WS_C3 + k0 + t]; csts[t] = ws[WS_CST + k0 + t]; }

  float y[4][16];
  float s1[4] = {0.f,0.f,0.f,0.f}, s2[4] = {0.f,0.f,0.f,0.f};
  #pragma unroll
  for (int j = 0; j < 4; ++j)
    #pragma unroll
    for (int l = 0; l < 16; ++l) y[j][l] = 0.f;

  for (int d0 = 0; d0 < DF; d0 += DT) {
    __syncthreads();
    // stage x tile: 128 rows x 32 d
    #pragma unroll
    for (int i = 0; i < 4; ++i) {
      int u = t + i*256;
      int row = u >> 3, d4 = u & 7;
      float4 v = *(const float4*)&x[(size_t)(n0+row)*DF + d0 + d4*4];
      xs[d4*4+0][row] = v.x; xs[d4*4+1][row] = v.y;
      xs[d4*4+2][row] = v.z; xs[d4*4+3][row] = v.w;
    }
    // stage A tile: 8 k x 32 d x 16 l (contiguous per k)
    #pragma unroll
    for (int i = 0; i < 4; ++i) {
      int u = t + i*256;
      int k2 = u >> 7, rem = u & 127;
      *(float4*)&As_[k2*516 + rem*4] =
          *(const float4*)&A[(size_t)((k0+k2)*DF + d0)*LF + rem*4];
    }
    // stage iD, MU: 8 k x 32 d
    {
      int k2 = t >> 5, dd = t & 31;
      float dv = Dm[(k0+k2)*DF + d0 + dd];
      iDs[k2][dd] = 1.f / (dv*dv);
      MUs[k2][dd] = MU[(k0+k2)*DF + d0 + dd];
    }
    __syncthreads();

    const float4* Ab = (const float4*)&As_[kk*516];
    #pragma unroll 2
    for (int dd = 0; dd < DT; ++dd) {
      float w  = iDs[kk][dd];
      float mu = MUs[kk][dd];
      float4 a0 = Ab[dd*4+0], a1 = Ab[dd*4+1], a2 = Ab[dd*4+2], a3 = Ab[dd*4+3];
      float av[16];
      av[0]=a0.x; av[1]=a0.y; av[2]=a0.z; av[3]=a0.w;
      av[4]=a1.x; av[5]=a1.y; av[6]=a1.z; av[7]=a1.w;
      av[8]=a2.x; av[9]=a2.y; av[10]=a2.z; av[11]=a2.w;
      av[12]=a3.x; av[13]=a3.y; av[14]=a3.z; av[15]=a3.w;
      #pragma unroll
      for (int j = 0; j < 4; ++j) {
        float xv = xs[dd][nr + j*32];
        float xw = xv * w;
        s1[j] = fmaf(xw, xv, s1[j]);
        s2[j] = fmaf(xw, mu, s2[j]);
        #pragma unroll
        for (int l = 0; l < 16; ++l) y[j][l] = fmaf(xw, av[l], y[j][l]);
      }
    }
  }
  __syncthreads();

  // epilogue
  #pragma unroll
  for (int j = 0; j < 4; ++j) {
    float yv[16];
    #pragma unroll
    for (int l = 0; l < 16; ++l) yv[l] = y[j][l] - bs[kk][l];
    float q = 0.f;
    #pragma unroll
    for (int l = 0; l < 16; ++l) {
      float acc = 0.f;
      #pragma unroll
      for (int m = 0; m < 16; ++m)
        acc = fmaf(iLs[kk][l*16+m], yv[m], acc);
      q = fmaf(acc, yv[l], q);
    }
    float res = csts[kk] - 0.5f*(s1[j] - 2.f*s2[j] + c3s[kk]) + 0.5f*q;
    out[(size_t)(n0 + nr + j*32)*KCOMP + k0 + kk] = res;
  }
}

extern "C" void kernel_launch(void* const* d_in, const int* in_sizes, int n_in,
                              void* d_out, int out_size, void* d_ws, size_t ws_size,
                              hipStream_t stream) {
  const float* x  = (const float*)d_in[0];
  const float* PI = (const float*)d_in[1];
  const float* MU = (const float*)d_in[2];
  const float* A  = (const float*)d_in[3];
  const float* Dm = (const float*)d_in[4];
  float* ws  = (float*)d_ws;
  float* out = (float*)d_out;

  mfa_pre<<<dim3(KCOMP), dim3(256), 0, stream>>>(PI, MU, A, Dm, ws);
  mfa_main<<<dim3(NPTS/BN, KCOMP/BK), dim3(256), 0, stream>>>(x, A, MU, Dm, ws, out);
}

// Round 2
// 223.006 us; speedup vs baseline: 8.9548x; 8.9548x over previous
//
#include <hip/hip_runtime.h>
#include <math.h>

#define KCOMP 128
#define DF    1024
#define LF    16
#define NPTS  16384
#define NG    8            // component groups of 16
#define CG    288          // B columns per group: 16*16 G + 16 h + 16 iD
#define BN    128
#define DT    32
#define PITCH 40           // LDS slab pitch in bf16 elems (uniform bank spread)

typedef __attribute__((ext_vector_type(8))) short short8v;
typedef __attribute__((ext_vector_type(4))) float f32x4;
typedef unsigned short ushort_t;

#define BMAT_ELEMS ((size_t)(NG*CG)*DF)   // 2304*1024 bf16
#define CST_OFF    (BMAT_ELEMS*2)          // byte offset of cst[128] in ws
#define MUH_OFF    (CST_OFF + 512)         // byte offset of muh[128]

__device__ __forceinline__ ushort_t f2bf(float f) {
  union { float f; unsigned u; } v; v.f = f;
  unsigned u = v.u;
  return (ushort_t)((u + 0x7FFFu + ((u >> 16) & 1u)) >> 16);
}

// ---------------------------------------------------------------------------
// Pre: per component k (128 blocks x 256 thr):
//   Lm = I + A^T iD A ; R = chol(Lm) ; z = Lm^{-1} b (b = (iDA)^T mu)
//   G = iDA R^{-T} ; h = iD*mu - iDA z ; muh = mu.h
//   Bmat cols (bf16, d-contiguous): group g=k/16, kl=k%16:
//     cols kl*16+l  : G[:,l]        (A-operand = x)
//     col  256+kl   : h             (A-operand = x)
//     col  272+kl   : iD            (A-operand = x^2)
//   cst[k] = PI[k] - 0.5*(DF*log2pi + 2*sum log R_jj - sum log iD)
// ---------------------------------------------------------------------------
__global__ __launch_bounds__(256) void mfa_pre(
    const float* __restrict__ PI, const float* __restrict__ MU,
    const float* __restrict__ A, const float* __restrict__ Dm,
    ushort_t* __restrict__ Bmat, float* __restrict__ cst, float* __restrict__ muh)
{
  const int k = blockIdx.x, t = threadIdx.x;
  const int tl = t >> 4, tm = t & 15;
  __shared__ float As[16][16], iDsh[16], MUsh[16];
  __shared__ float R[16][17], rinv[16], zsh[16], bsh[16];
  __shared__ float red[256];

  float accL = 0.f, accb = 0.f, slog = 0.f;
  for (int d0 = 0; d0 < DF; d0 += 16) {
    __syncthreads();
    As[tl][tm] = A[((size_t)k*DF + d0 + tl)*LF + tm];
    if (t < 16) {
      float dv = Dm[k*DF + d0 + t];
      iDsh[t] = 1.f/(dv*dv);
      MUsh[t] = MU[k*DF + d0 + t];
    }
    __syncthreads();
    #pragma unroll
    for (int dd = 0; dd < 16; ++dd) {
      float w = iDsh[dd];
      accL = fmaf(As[dd][tl]*w, As[dd][tm], accL);
    }
    if (tm == 0) {
      #pragma unroll
      for (int dd = 0; dd < 16; ++dd)
        accb = fmaf(iDsh[dd]*MUsh[dd], As[dd][tl], accb);
    }
    if (t < 16) slog += logf(iDsh[t]);
  }
  __syncthreads();
  R[tl][tm] = accL + (tl == tm ? 1.f : 0.f);
  if (tm == 0) bsh[tl] = accb;
  red[t] = (t < 16) ? slog : 0.f;
  __syncthreads();

  float sumlogiD = 0.f;
  if (t == 0) { for (int i = 0; i < 16; ++i) sumlogiD += red[i]; }

  // in-place Cholesky (lower), no pivoting (SPD, diag-dominant)
  for (int j = 0; j < 16; ++j) {
    if (t == j) {
      float s = R[j][j];
      for (int i = 0; i < j; ++i) s -= R[j][i]*R[j][i];
      float rj = sqrtf(s);
      R[j][j] = rj; rinv[j] = 1.f/rj;
    }
    __syncthreads();
    if (t < 16 && t > j) {
      float s = R[t][j];
      for (int i = 0; i < j; ++i) s -= R[t][i]*R[j][i];
      R[t][j] = s * rinv[j];
    }
    __syncthreads();
  }

  float ldet = 0.f;
  if (t == 0) {
    #pragma unroll
    for (int j = 0; j < 16; ++j) ldet += 2.f*logf(R[j][j]);
    float w[16], z[16];
    #pragma unroll
    for (int j = 0; j < 16; ++j) {
      float s = bsh[j];
      #pragma unroll
      for (int i = 0; i < 16; ++i) if (i < j) s -= R[j][i]*w[i];
      w[j] = s*rinv[j];
    }
    #pragma unroll
    for (int j = 15; j >= 0; --j) {
      float s = w[j];
      #pragma unroll
      for (int i = 0; i < 16; ++i) if (i > j) s -= R[i][j]*z[i];
      z[j] = s*rinv[j];
      zsh[j] = z[j];
    }
  }
  __syncthreads();

  const int g = k >> 4, kl = k & 15;
  ushort_t* Bg = Bmat + (size_t)g*CG*DF;
  float muhp = 0.f;
  for (int it = 0; it < 4; ++it) {
    int d = t + it*256;
    float dv = Dm[k*DF + d];
    float iD = 1.f/(dv*dv);
    float mu = MU[k*DF + d];
    float v[16], gg[16];
    #pragma unroll
    for (int l = 0; l < 16; ++l) v[l] = iD * A[((size_t)k*DF + d)*LF + l];
    #pragma unroll
    for (int j = 0; j < 16; ++j) {
      float s = v[j];
      #pragma unroll
      for (int i = 0; i < 16; ++i) if (i < j) s -= R[j][i]*gg[i];
      gg[j] = s * rinv[j];
    }
    float h = iD*mu;
    #pragma unroll
    for (int l = 0; l < 16; ++l) h -= v[l]*zsh[l];
    muhp = fmaf(mu, h, muhp);
    #pragma unroll
    for (int l = 0; l < 16; ++l)
      Bg[(size_t)(kl*16 + l)*DF + d] = f2bf(gg[l]);
    Bg[(size_t)(256 + kl)*DF + d] = f2bf(h);
    Bg[(size_t)(272 + kl)*DF + d] = f2bf(iD);
  }
  red[t] = muhp;
  __syncthreads();
  for (int s = 128; s > 0; s >>= 1) {
    if (t < s) red[t] += red[t + s];
    __syncthreads();
  }
  if (t == 0) {
    const float LOG2PI = 1.8378770664093453f;
    muh[k] = red[0];
    cst[k] = PI[k] - 0.5f*((float)DF*LOG2PI + ldet - sumlogiD);
  }
}

// ---------------------------------------------------------------------------
// Main: block = 128 n-rows x one group (288 cols), 512 thr = 8 waves (4r x 2c).
// Wave: 32 rows x 144 cols = 2x9 tiles of mfma_f32_16x16x32_bf16.
// Col tiles 0..15 = y (G) per comp; 16 = h-dot; 17 = s1 (A-operand x^2).
// Epilogue: m_d = s1 - sum_l y_l^2 - 2*s2 + muh ; out = cst - 0.5*m_d.
// ---------------------------------------------------------------------------
__global__ __launch_bounds__(512, 2) void mfa_main(
    const float* __restrict__ x, const ushort_t* __restrict__ Bmat,
    const float* __restrict__ cst, const float* __restrict__ muh,
    float* __restrict__ out)
{
  __shared__ __align__(16) ushort_t smem[2*BN*PITCH + CG*PITCH];
  ushort_t* xs  = smem;
  ushort_t* x2s = smem + BN*PITCH;
  ushort_t* Bs  = smem + 2*BN*PITCH;

  const int t = threadIdx.x;
  const int lane = t & 63, wid = t >> 6;
  const int wr = wid & 3, wc = wid >> 2;
  const int lr = lane & 15, lh = lane >> 4;
  const int n0 = blockIdx.x * BN;
  const int g  = blockIdx.y;

  f32x4 acc[2][9] = {};

  const int srow = t >> 2, sc = t & 3;

  int xoff[2];
  #pragma unroll
  for (int rt = 0; rt < 2; ++rt)
    xoff[rt] = (wr*32 + rt*16 + lr)*PITCH + lh*8;
  int boff[9];
  #pragma unroll
  for (int ct = 0; ct < 9; ++ct)
    boff[ct] = (wc*144 + ct*16 + lr)*PITCH + lh*8;

  for (int d0 = 0; d0 < DF; d0 += DT) {
    __syncthreads();
    {
      const float* xp = x + (size_t)(n0 + srow)*DF + d0 + sc*8;
      float4 v0 = *(const float4*)xp;
      float4 v1 = *(const float4*)(xp + 4);
      float e[8] = {v0.x,v0.y,v0.z,v0.w,v1.x,v1.y,v1.z,v1.w};
      short8v xv, qv;
      #pragma unroll
      for (int i = 0; i < 8; ++i) {
        xv[i] = (short)f2bf(e[i]);
        qv[i] = (short)f2bf(e[i]*e[i]);
      }
      *(short8v*)&xs[srow*PITCH + sc*8]  = xv;
      *(short8v*)&x2s[srow*PITCH + sc*8] = qv;
    }
    for (int u = t; u < CG*4; u += 512) {
      int col = u >> 2, c = u & 3;
      *(short8v*)&Bs[col*PITCH + c*8] =
        *(const short8v*)&Bmat[((size_t)(g*CG + col))*DF + d0 + c*8];
    }
    __syncthreads();

    short8v xf[2];
    #pragma unroll
    for (int rt = 0; rt < 2; ++rt) xf[rt] = *(short8v*)&xs[xoff[rt]];

    #pragma unroll
    for (int ct = 0; ct < 8; ++ct) {
      short8v bf = *(short8v*)&Bs[boff[ct]];
      #pragma unroll
      for (int rt = 0; rt < 2; ++rt)
        acc[rt][ct] = __builtin_amdgcn_mfma_f32_16x16x32_bf16(xf[rt], bf, acc[rt][ct], 0, 0, 0);
    }
    {
      short8v bf = *(short8v*)&Bs[boff[8]];
      short8v a0 = xf[0], a1 = xf[1];
      if (wc) {
        a0 = *(short8v*)&x2s[xoff[0]];
        a1 = *(short8v*)&x2s[xoff[1]];
      }
      acc[0][8] = __builtin_amdgcn_mfma_f32_16x16x32_bf16(a0, bf, acc[0][8], 0, 0, 0);
      acc[1][8] = __builtin_amdgcn_mfma_f32_16x16x32_bf16(a1, bf, acc[1][8], 0, 0, 0);
    }
  }

  __syncthreads();
  float* s1v = (float*)smem;
  float* s2h = s1v + BN*17;
  if (wc == 1) {
    #pragma unroll
    for (int rt = 0; rt < 2; ++rt)
      #pragma unroll
      for (int j = 0; j < 4; ++j) {
        int row = wr*32 + rt*16 + lh*4 + j;
        s2h[row*17 + lr] = acc[rt][7][j];   // global tile 16: x.h
        s1v[row*17 + lr] = acc[rt][8][j];   // global tile 17: s1
      }
  }
  __syncthreads();

  const int nyt = wc ? 7 : 9;
  #pragma unroll
  for (int ct = 0; ct < 9; ++ct) {
    if (ct < nyt) {
      int comp = wc*9 + ct;
      int kk = g*16 + comp;
      float cstk = cst[kk], muhk = muh[kk];
      #pragma unroll
      for (int rt = 0; rt < 2; ++rt)
        #pragma unroll
        for (int j = 0; j < 4; ++j) {
          float yv = acc[rt][ct][j];
          float sq = yv*yv;
          sq += __shfl_xor(sq, 1);
          sq += __shfl_xor(sq, 2);
          sq += __shfl_xor(sq, 4);
          sq += __shfl_xor(sq, 8);
          int row = wr*32 + rt*16 + lh*4 + j;
          float s1 = s1v[row*17 + comp];
          float s2 = s2h[row*17 + comp];
          float res = cstk - 0.5f*(s1 - sq - 2.f*s2 + muhk);
          if (lr == 0) out[(size_t)(n0 + row)*KCOMP + kk] = res;
        }
    }
  }
}

extern "C" void kernel_launch(void* const* d_in, const int* in_sizes, int n_in,
                              void* d_out, int out_size, void* d_ws, size_t ws_size,
                              hipStream_t stream) {
  const float* x  = (const float*)d_in[0];
  const float* PI = (const float*)d_in[1];
  const float* MU = (const float*)d_in[2];
  const float* A  = (const float*)d_in[3];
  const float* Dm = (const float*)d_in[4];
  ushort_t* Bmat = (ushort_t*)d_ws;
  float* cstp = (float*)((char*)d_ws + CST_OFF);
  float* muhp = (float*)((char*)d_ws + MUH_OFF);
  float* out = (float*)d_out;

  mfa_pre<<<dim3(KCOMP), dim3(256), 0, stream>>>(PI, MU, A, Dm, Bmat, cstp, muhp);
  mfa_main<<<dim3(NPTS/BN, NG), dim3(512), 0, stream>>>(x, Bmat, cstp, muhp, out);
}